// Round 2
// baseline (579.982 us; speedup 1.0000x reference)
//
#include <hip/hip_runtime.h>

#define B_ 4
#define T_ 4096
#define C_ 1024
#define H_ 128

typedef __attribute__((ext_vector_type(8))) __bf16 bf16x8;
typedef __attribute__((ext_vector_type(8))) unsigned short u16x8;
typedef __attribute__((ext_vector_type(4))) float f32x4;

__device__ __forceinline__ unsigned short f2bf(float f) {
  unsigned int u = __float_as_uint(f);
  return (unsigned short)((u + 0x7FFFu + ((u >> 16) & 1u)) >> 16);
}
__device__ __forceinline__ float bf2f(unsigned short h) {
  return __uint_as_float((unsigned)h << 16);
}
__device__ __forceinline__ bf16x8 ldb8(const unsigned short* p) {
  return *(const bf16x8*)(const void*)p;
}
// load 8 fp32, emit hi/lo bf16x8 fragments (hi+lo error ~2^-18 rel)
__device__ __forceinline__ void split8(const float* p, bf16x8& hi, bf16x8& lo) {
  float f[8];
  *(f32x4*)&f[0] = *(const f32x4*)(const void*)p;
  *(f32x4*)&f[4] = *(const f32x4*)(const void*)(p + 4);
  u16x8 h, l;
#pragma unroll
  for (int j = 0; j < 8; j++) {
    h[j] = f2bf(f[j]);
    l[j] = f2bf(f[j] - bf2f(h[j]));
  }
  hi = __builtin_bit_cast(bf16x8, h);
  lo = __builtin_bit_cast(bf16x8, l);
}

// ---------------------------------------------------------------------------
// Kernel 1: W [C][H] fp32 (x3) -> Wthi/Wtlo [3][H][C] bf16 (transpose + split)
// ---------------------------------------------------------------------------
__global__ void wt_k(const float* __restrict__ Wq, const float* __restrict__ Wk,
                     const float* __restrict__ Wv, unsigned short* __restrict__ Whi,
                     unsigned short* __restrict__ Wlo) {
  __shared__ float tile[32][33];
  int m = blockIdx.z;
  const float* W = (m == 0) ? Wq : ((m == 1) ? Wk : Wv);
  int c0 = blockIdx.x * 32, h0 = blockIdx.y * 32;
  int tx = threadIdx.x, ty = threadIdx.y;  // 32 x 8
#pragma unroll
  for (int i = 0; i < 4; i++)
    tile[ty + 8 * i][tx] = W[(size_t)(c0 + ty + 8 * i) * H_ + h0 + tx];
  __syncthreads();
  size_t base = (size_t)m * H_ * C_;
#pragma unroll
  for (int i = 0; i < 4; i++) {
    float f = tile[tx][ty + 8 * i];
    unsigned short hi = f2bf(f);
    unsigned short lo = f2bf(f - bf2f(hi));
    size_t idx = base + (size_t)(h0 + ty + 8 * i) * C_ + c0 + tx;
    Whi[idx] = hi;
    Wlo[idx] = lo;
  }
}

// ---------------------------------------------------------------------------
// Kernel 2: fused QKV projection, split-bf16 precision for Q,K.
// Q,K written fp32 [B*T][H]; V written transposed bf16 Vt[b][h][t].
// ---------------------------------------------------------------------------
#define WP 40  // LDS pitch: keeps ds_read_b128 at the free 2-way bank pattern
__global__ __launch_bounds__(256) void qkv_k(
    const float* __restrict__ x, const unsigned short* __restrict__ Whi,
    const unsigned short* __restrict__ Wlo, float* __restrict__ Qf,
    float* __restrict__ Kf, unsigned short* __restrict__ Vt) {
  int m = blockIdx.x % 3;
  int r0 = (blockIdx.x / 3) * 64;
  __shared__ unsigned short whi[128 * WP];
  __shared__ unsigned short wlo[128 * WP];
  int tid = threadIdx.x;
  int lane = tid & 63, wave = tid >> 6;
  int l15 = lane & 15, quad = lane >> 4;
  const unsigned short* Wmh = Whi + (size_t)m * H_ * C_;
  const unsigned short* Wml = Wlo + (size_t)m * H_ * C_;
  f32x4 acc[8];
#pragma unroll
  for (int n = 0; n < 8; n++) acc[n] = (f32x4){0.f, 0.f, 0.f, 0.f};
  int wrow = r0 + wave * 16 + l15;  // A-fragment row for this lane
  const float* xrow = x + (size_t)wrow * C_;

  for (int k0 = 0; k0 < C_; k0 += 32) {
    __syncthreads();
    // stage Whi (and Wlo for Q,K) tile: 128 rows x 32 cols, 16B chunks
#pragma unroll
    for (int it = 0; it < 2; it++) {
      int c = it * 256 + tid;
      int h = c >> 2, kc = c & 3;
      *(int4*)(void*)(whi + h * WP + kc * 8) =
          *(const int4*)(const void*)(Wmh + (size_t)h * C_ + k0 + kc * 8);
      if (m < 2)
        *(int4*)(void*)(wlo + h * WP + kc * 8) =
            *(const int4*)(const void*)(Wml + (size_t)h * C_ + k0 + kc * 8);
    }
    __syncthreads();
    // A fragments: x fp32 -> hi/lo bf16, row=l15, k=quad*8+j
    bf16x8 ahi, alo;
    split8(xrow + k0 + quad * 8, ahi, alo);
    if (m < 2) {
#pragma unroll
      for (int n = 0; n < 8; n++) {
        bf16x8 bhi = ldb8(whi + (n * 16 + l15) * WP + quad * 8);
        bf16x8 blo = ldb8(wlo + (n * 16 + l15) * WP + quad * 8);
        acc[n] = __builtin_amdgcn_mfma_f32_16x16x32_bf16(ahi, bhi, acc[n], 0, 0, 0);
        acc[n] = __builtin_amdgcn_mfma_f32_16x16x32_bf16(alo, bhi, acc[n], 0, 0, 0);
        acc[n] = __builtin_amdgcn_mfma_f32_16x16x32_bf16(ahi, blo, acc[n], 0, 0, 0);
      }
    } else {
#pragma unroll
      for (int n = 0; n < 8; n++) {
        bf16x8 bhi = ldb8(whi + (n * 16 + l15) * WP + quad * 8);
        acc[n] = __builtin_amdgcn_mfma_f32_16x16x32_bf16(ahi, bhi, acc[n], 0, 0, 0);
      }
    }
  }
  // epilogue: C-layout row = quad*4+r, col = n*16+l15
  int ob = r0 + wave * 16 + quad * 4;
  if (m < 2) {
    float* O = (m == 0) ? Qf : Kf;
#pragma unroll
    for (int n = 0; n < 8; n++)
#pragma unroll
      for (int r = 0; r < 4; r++)
        O[(size_t)(ob + r) * H_ + n * 16 + l15] = acc[n][r];
  } else {
#pragma unroll
    for (int n = 0; n < 8; n++)
#pragma unroll
      for (int r = 0; r < 4; r++) {
        int gr = ob + r;
        int bb = gr >> 12, t = gr & (T_ - 1);
        Vt[((size_t)bb * H_ + n * 16 + l15) * T_ + t] = f2bf(acc[n][r]);
      }
  }
}

// ---------------------------------------------------------------------------
// Kernel 3: flash attention, 1 wave per 16-row Q tile, Bc=64 KV tiles.
// Q,K: fp32 [b][t][h] split to hi/lo bf16 fragments on the fly (exact logits
// to ~2^-18); Vt: bf16 [b][h][t]; out: fp32 [b][t][h].
// ---------------------------------------------------------------------------
#define PP 72  // P-buffer pitch: 2-way-free bank pattern for b128 reads
__global__ __launch_bounds__(64) void flash_k(
    const float* __restrict__ Q, const float* __restrict__ K,
    const unsigned short* __restrict__ Vt, float* __restrict__ out) {
  __shared__ unsigned short pbuf[16 * PP];
  // XCD-affine mapping: batch = (blockIdx&7)>>1 keeps each XCD's K/V working
  // set (~3MB) inside its 4MB L2. Longest q-tiles first (LPT balancing).
  int g = blockIdx.x & 7;
  int j = blockIdx.x >> 3;  // 0..127
  int b = g >> 1;
  int i = 255 - (2 * j + (g & 1));  // q-tile index within batch, descending
  int q0 = i * 16;
  int lane = threadIdx.x;
  int l15 = lane & 15, quad = lane >> 4;
  const float* Qb = Q + (size_t)b * T_ * H_;
  const float* Kb = K + (size_t)b * T_ * H_;
  const unsigned short* Vb = Vt + (size_t)b * H_ * T_;

  bf16x8 qhi[4], qlo[4];
  {
    const float* qr = Qb + (size_t)(q0 + l15) * H_ + quad * 8;
#pragma unroll
    for (int kk = 0; kk < 4; kk++) split8(qr + kk * 32, qhi[kk], qlo[kk]);
  }
  f32x4 o[8];
#pragma unroll
  for (int n = 0; n < 8; n++) o[n] = (f32x4){0.f, 0.f, 0.f, 0.f};
  float mr[4] = {-1e30f, -1e30f, -1e30f, -1e30f};
  float lr[4] = {0.f, 0.f, 0.f, 0.f};

  int ktd = q0 >> 6;  // diagonal (masked) tile; all earlier tiles full
  for (int kt = 0; kt <= ktd; kt++) {
    // S = Q @ K^T (16 x 64), split-precision: hi*hi + lo*hi + hi*lo
    f32x4 s[4];
#pragma unroll
    for (int n = 0; n < 4; n++) s[n] = (f32x4){0.f, 0.f, 0.f, 0.f};
#pragma unroll
    for (int n = 0; n < 4; n++) {
      const float* kr = Kb + (size_t)(kt * 64 + n * 16 + l15) * H_ + quad * 8;
#pragma unroll
      for (int kk = 0; kk < 4; kk++) {
        bf16x8 khi, klo;
        split8(kr + kk * 32, khi, klo);
        s[n] = __builtin_amdgcn_mfma_f32_16x16x32_bf16(qhi[kk], khi, s[n], 0, 0, 0);
        s[n] = __builtin_amdgcn_mfma_f32_16x16x32_bf16(qlo[kk], khi, s[n], 0, 0, 0);
        s[n] = __builtin_amdgcn_mfma_f32_16x16x32_bf16(qhi[kk], klo, s[n], 0, 0, 0);
      }
    }
    if (kt == ktd) {  // causal mask on diagonal tile
#pragma unroll
      for (int n = 0; n < 4; n++) {
        int col = kt * 64 + n * 16 + l15;
#pragma unroll
        for (int r = 0; r < 4; r++) {
          int row = q0 + quad * 4 + r;
          if (col > row) s[n][r] = -1e30f;
        }
      }
    }
    // online softmax: rows on (quad, r); reduce across the 16 l15 lanes
    float mnew[4];
#pragma unroll
    for (int r = 0; r < 4; r++)
      mnew[r] = fmaxf(fmaxf(s[0][r], s[1][r]), fmaxf(s[2][r], s[3][r]));
#pragma unroll
    for (int off = 1; off < 16; off <<= 1)
#pragma unroll
      for (int r = 0; r < 4; r++) mnew[r] = fmaxf(mnew[r], __shfl_xor(mnew[r], off));
    float alpha[4];
#pragma unroll
    for (int r = 0; r < 4; r++) {
      float mi = fmaxf(mr[r], mnew[r]);
      alpha[r] = __expf(mr[r] - mi);
      mr[r] = mi;
    }
    float p[4][4], rs[4];
#pragma unroll
    for (int n = 0; n < 4; n++)
#pragma unroll
      for (int r = 0; r < 4; r++) p[n][r] = __expf(s[n][r] - mr[r]);
#pragma unroll
    for (int r = 0; r < 4; r++) rs[r] = (p[0][r] + p[1][r]) + (p[2][r] + p[3][r]);
#pragma unroll
    for (int off = 1; off < 16; off <<= 1)
#pragma unroll
      for (int r = 0; r < 4; r++) rs[r] += __shfl_xor(rs[r], off);
#pragma unroll
    for (int r = 0; r < 4; r++) lr[r] = lr[r] * alpha[r] + rs[r];
#pragma unroll
    for (int n = 0; n < 8; n++)
#pragma unroll
      for (int r = 0; r < 4; r++) o[n][r] *= alpha[r];
    // P: C-layout -> A-layout via LDS
    __syncthreads();
#pragma unroll
    for (int n = 0; n < 4; n++)
#pragma unroll
      for (int r = 0; r < 4; r++)
        pbuf[(quad * 4 + r) * PP + n * 16 + l15] = f2bf(p[n][r]);
    __syncthreads();
    // O += P @ V (V pre-transposed: contiguous B-fragments)
#pragma unroll
    for (int ks = 0; ks < 2; ks++) {
      bf16x8 pa = ldb8(pbuf + l15 * PP + ks * 32 + quad * 8);
#pragma unroll
      for (int n = 0; n < 8; n++) {
        bf16x8 vf = ldb8(Vb + (size_t)(n * 16 + l15) * T_ + kt * 64 + ks * 32 + quad * 8);
        o[n] = __builtin_amdgcn_mfma_f32_16x16x32_bf16(pa, vf, o[n], 0, 0, 0);
      }
    }
  }
  float inv[4];
#pragma unroll
  for (int r = 0; r < 4; r++) inv[r] = 1.0f / lr[r];
  float* orow = out + ((size_t)b * T_ + q0 + quad * 4) * H_;
#pragma unroll
  for (int n = 0; n < 8; n++)
#pragma unroll
    for (int r = 0; r < 4; r++)
      orow[(size_t)r * H_ + n * 16 + l15] = o[n][r] * inv[r];
}

// ---------------------------------------------------------------------------
extern "C" void kernel_launch(void* const* d_in, const int* in_sizes, int n_in,
                              void* d_out, int out_size, void* d_ws, size_t ws_size,
                              hipStream_t stream) {
  const float* x  = (const float*)d_in[0];
  const float* Wq = (const float*)d_in[1];
  const float* Wk = (const float*)d_in[2];
  const float* Wv = (const float*)d_in[3];
  // ws layout (21.5 MB): Whi | Wlo | Vt (u16), then Qf | Kf (f32)
  unsigned short* Whi = (unsigned short*)d_ws;          // 3*128*1024
  unsigned short* Wlo = Whi + 3 * H_ * C_;
  unsigned short* Vt  = Wlo + 3 * H_ * C_;              // B*T*H
  float* Qf = (float*)(void*)(Vt + (size_t)B_ * T_ * H_);
  float* Kf = Qf + (size_t)B_ * T_ * H_;
  float* out = (float*)d_out;

  wt_k<<<dim3(32, 4, 3), dim3(32, 8), 0, stream>>>(Wq, Wk, Wv, Whi, Wlo);
  qkv_k<<<3 * (B_ * T_ / 64), 256, 0, stream>>>(x, Whi, Wlo, Qf, Kf, Vt);
  flash_k<<<B_ * (T_ / 16), 64, 0, stream>>>(Qf, Kf, Vt, out);
}

// Round 3
// 402.246 us; speedup vs baseline: 1.4419x; 1.4419x over previous
//
#include <hip/hip_runtime.h>

#define B_ 4
#define T_ 4096
#define C_ 1024
#define H_ 128

typedef __attribute__((ext_vector_type(8))) __bf16 bf16x8;
typedef __attribute__((ext_vector_type(8))) unsigned short u16x8;
typedef __attribute__((ext_vector_type(4))) float f32x4;

__device__ __forceinline__ unsigned short f2bf(float f) {
  unsigned int u = __float_as_uint(f);
  return (unsigned short)((u + 0x7FFFu + ((u >> 16) & 1u)) >> 16);
}
__device__ __forceinline__ float bf2f(unsigned short h) {
  return __uint_as_float((unsigned)h << 16);
}
__device__ __forceinline__ bf16x8 ldb8(const unsigned short* p) {
  return *(const bf16x8*)(const void*)p;
}
// load 8 fp32, emit hi/lo bf16x8 fragments (hi+lo error ~2^-18 rel)
__device__ __forceinline__ void split8(const float* p, bf16x8& hi, bf16x8& lo) {
  float f[8];
  *(f32x4*)&f[0] = *(const f32x4*)(const void*)p;
  *(f32x4*)&f[4] = *(const f32x4*)(const void*)(p + 4);
  u16x8 h, l;
#pragma unroll
  for (int j = 0; j < 8; j++) {
    h[j] = f2bf(f[j]);
    l[j] = f2bf(f[j] - bf2f(h[j]));
  }
  hi = __builtin_bit_cast(bf16x8, h);
  lo = __builtin_bit_cast(bf16x8, l);
}

// ---------------------------------------------------------------------------
// Kernel 1: W [C][H] fp32 (x3) -> Wthi/Wtlo [.][H][C] bf16 (transpose + split)
// Wlo only produced for Q,K (m<2): V needs only single-product precision.
// ---------------------------------------------------------------------------
__global__ void wt_k(const float* __restrict__ Wq, const float* __restrict__ Wk,
                     const float* __restrict__ Wv, unsigned short* __restrict__ Whi,
                     unsigned short* __restrict__ Wlo) {
  __shared__ float tile[32][33];
  int m = blockIdx.z;
  const float* W = (m == 0) ? Wq : ((m == 1) ? Wk : Wv);
  int c0 = blockIdx.x * 32, h0 = blockIdx.y * 32;
  int tx = threadIdx.x, ty = threadIdx.y;  // 32 x 8
#pragma unroll
  for (int i = 0; i < 4; i++)
    tile[ty + 8 * i][tx] = W[(size_t)(c0 + ty + 8 * i) * H_ + h0 + tx];
  __syncthreads();
  size_t base = (size_t)m * H_ * C_;
#pragma unroll
  for (int i = 0; i < 4; i++) {
    float f = tile[tx][ty + 8 * i];
    unsigned short hi = f2bf(f);
    size_t idx = base + (size_t)(h0 + ty + 8 * i) * C_ + c0 + tx;
    Whi[idx] = hi;
    if (m < 2) Wlo[idx] = f2bf(f - bf2f(hi));
  }
}

// ---------------------------------------------------------------------------
// Kernel 2: fused QKV projection, split-bf16 precision for Q,K.
// Writes Q,K PRE-SPLIT: Qhi/Qlo/Khi/Klo bf16 [B*T][H] (split is O(T) here,
// was O(T^2) when done per-tile in flash). V written transposed bf16 Vt[b][h][t].
// ---------------------------------------------------------------------------
#define WP 40  // LDS pitch: keeps ds_read_b128 at the free 2-way bank pattern
__global__ __launch_bounds__(256) void qkv_k(
    const float* __restrict__ x, const unsigned short* __restrict__ Whi,
    const unsigned short* __restrict__ Wlo, unsigned short* __restrict__ Qhi,
    unsigned short* __restrict__ Qlo, unsigned short* __restrict__ Khi,
    unsigned short* __restrict__ Klo, unsigned short* __restrict__ Vt) {
  int m = blockIdx.x % 3;
  int r0 = (blockIdx.x / 3) * 64;
  __shared__ unsigned short whi[128 * WP];
  __shared__ unsigned short wlo[128 * WP];
  int tid = threadIdx.x;
  int lane = tid & 63, wave = tid >> 6;
  int l15 = lane & 15, quad = lane >> 4;
  const unsigned short* Wmh = Whi + (size_t)m * H_ * C_;
  const unsigned short* Wml = Wlo + (size_t)m * H_ * C_;
  f32x4 acc[8];
#pragma unroll
  for (int n = 0; n < 8; n++) acc[n] = (f32x4){0.f, 0.f, 0.f, 0.f};
  int wrow = r0 + wave * 16 + l15;  // A-fragment row for this lane
  const float* xrow = x + (size_t)wrow * C_;

  for (int k0 = 0; k0 < C_; k0 += 32) {
    __syncthreads();
    // stage Whi (and Wlo for Q,K) tile: 128 rows x 32 cols, 16B chunks
#pragma unroll
    for (int it = 0; it < 2; it++) {
      int c = it * 256 + tid;
      int h = c >> 2, kc = c & 3;
      *(int4*)(void*)(whi + h * WP + kc * 8) =
          *(const int4*)(const void*)(Wmh + (size_t)h * C_ + k0 + kc * 8);
      if (m < 2)
        *(int4*)(void*)(wlo + h * WP + kc * 8) =
            *(const int4*)(const void*)(Wml + (size_t)h * C_ + k0 + kc * 8);
    }
    __syncthreads();
    // A fragments: x fp32 -> hi/lo bf16, row=l15, k=quad*8+j
    bf16x8 ahi, alo;
    split8(xrow + k0 + quad * 8, ahi, alo);
    if (m < 2) {
#pragma unroll
      for (int n = 0; n < 8; n++) {
        bf16x8 bhi = ldb8(whi + (n * 16 + l15) * WP + quad * 8);
        bf16x8 blo = ldb8(wlo + (n * 16 + l15) * WP + quad * 8);
        acc[n] = __builtin_amdgcn_mfma_f32_16x16x32_bf16(ahi, bhi, acc[n], 0, 0, 0);
        acc[n] = __builtin_amdgcn_mfma_f32_16x16x32_bf16(alo, bhi, acc[n], 0, 0, 0);
        acc[n] = __builtin_amdgcn_mfma_f32_16x16x32_bf16(ahi, blo, acc[n], 0, 0, 0);
      }
    } else {
#pragma unroll
      for (int n = 0; n < 8; n++) {
        bf16x8 bhi = ldb8(whi + (n * 16 + l15) * WP + quad * 8);
        acc[n] = __builtin_amdgcn_mfma_f32_16x16x32_bf16(ahi, bhi, acc[n], 0, 0, 0);
      }
    }
  }
  // epilogue: C-layout row = quad*4+r, col = n*16+l15
  int ob = r0 + wave * 16 + quad * 4;
  if (m < 2) {
    unsigned short* Oh = (m == 0) ? Qhi : Khi;
    unsigned short* Ol = (m == 0) ? Qlo : Klo;
#pragma unroll
    for (int n = 0; n < 8; n++)
#pragma unroll
      for (int r = 0; r < 4; r++) {
        float f = acc[n][r];
        unsigned short hi = f2bf(f);
        size_t idx = (size_t)(ob + r) * H_ + n * 16 + l15;
        Oh[idx] = hi;
        Ol[idx] = f2bf(f - bf2f(hi));
      }
  } else {
#pragma unroll
    for (int n = 0; n < 8; n++)
#pragma unroll
      for (int r = 0; r < 4; r++) {
        int gr = ob + r;
        int bb = gr >> 12, t = gr & (T_ - 1);
        Vt[((size_t)bb * H_ + n * 16 + l15) * T_ + t] = f2bf(acc[n][r]);
      }
  }
}

// ---------------------------------------------------------------------------
// Kernel 3: flash attention, 1 wave per 16-row Q tile, Bc=64 KV tiles.
// All operands pre-split bf16: zero conversion VALU in the O(T^2) loop.
// Single-wave blocks: LDS ordering needs only lgkmcnt, NOT __syncthreads
// (whose vmcnt(0) drain would serialize the load pipeline).
// ---------------------------------------------------------------------------
#define PP 72  // P-buffer pitch: 2-way-free bank pattern for b128 reads
__global__ __launch_bounds__(64, 1) void flash_k(
    const unsigned short* __restrict__ Qhi, const unsigned short* __restrict__ Qlo,
    const unsigned short* __restrict__ Khi, const unsigned short* __restrict__ Klo,
    const unsigned short* __restrict__ Vt, float* __restrict__ out) {
  __shared__ unsigned short pbuf[16 * PP];
  // XCD-affine mapping: batch = (blockIdx&7)>>1 keeps each XCD's K/V working
  // set inside its 4MB L2. Longest q-tiles first.
  int g = blockIdx.x & 7;
  int j = blockIdx.x >> 3;  // 0..127
  int b = g >> 1;
  int i = 255 - (2 * j + (g & 1));  // q-tile index within batch, descending
  int q0 = i * 16;
  int lane = threadIdx.x;
  int l15 = lane & 15, quad = lane >> 4;
  size_t boff = (size_t)b * T_ * H_;
  const unsigned short* Khb = Khi + boff;
  const unsigned short* Klb = Klo + boff;
  const unsigned short* Vb = Vt + (size_t)b * H_ * T_;

  bf16x8 qh[4], ql[4];
  {
    const unsigned short* qrh = Qhi + boff + (size_t)(q0 + l15) * H_ + quad * 8;
    const unsigned short* qrl = Qlo + boff + (size_t)(q0 + l15) * H_ + quad * 8;
#pragma unroll
    for (int kk = 0; kk < 4; kk++) {
      qh[kk] = ldb8(qrh + kk * 32);
      ql[kk] = ldb8(qrl + kk * 32);
    }
  }
  f32x4 o[8];
#pragma unroll
  for (int n = 0; n < 8; n++) o[n] = (f32x4){0.f, 0.f, 0.f, 0.f};
  float mr[4] = {-1e30f, -1e30f, -1e30f, -1e30f};
  float lr[4] = {0.f, 0.f, 0.f, 0.f};

  int ktd = q0 >> 6;  // diagonal (masked) tile; all earlier tiles full
  for (int kt = 0; kt <= ktd; kt++) {
    // S = Q @ K^T (16 x 64), split-precision: hi*hi + lo*hi + hi*lo
    f32x4 s[4];
#pragma unroll
    for (int n = 0; n < 4; n++) s[n] = (f32x4){0.f, 0.f, 0.f, 0.f};
#pragma unroll
    for (int n = 0; n < 4; n++) {
      size_t ro = (size_t)(kt * 64 + n * 16 + l15) * H_ + quad * 8;
      bf16x8 kh[4], kl[4];
#pragma unroll
      for (int kk = 0; kk < 4; kk++) {
        kh[kk] = ldb8(Khb + ro + kk * 32);
        kl[kk] = ldb8(Klb + ro + kk * 32);
      }
#pragma unroll
      for (int kk = 0; kk < 4; kk++) {
        s[n] = __builtin_amdgcn_mfma_f32_16x16x32_bf16(qh[kk], kh[kk], s[n], 0, 0, 0);
        s[n] = __builtin_amdgcn_mfma_f32_16x16x32_bf16(ql[kk], kh[kk], s[n], 0, 0, 0);
        s[n] = __builtin_amdgcn_mfma_f32_16x16x32_bf16(qh[kk], kl[kk], s[n], 0, 0, 0);
      }
    }
    // prefetch both V fragment groups now; softmax VALU hides their latency
    bf16x8 vf[2][8];
#pragma unroll
    for (int ks = 0; ks < 2; ks++)
#pragma unroll
      for (int n = 0; n < 8; n++)
        vf[ks][n] = ldb8(Vb + (size_t)(n * 16 + l15) * T_ + kt * 64 + ks * 32 + quad * 8);
    if (kt == ktd) {  // causal mask on diagonal tile
#pragma unroll
      for (int n = 0; n < 4; n++) {
        int col = kt * 64 + n * 16 + l15;
#pragma unroll
        for (int r = 0; r < 4; r++) {
          int row = q0 + quad * 4 + r;
          if (col > row) s[n][r] = -1e30f;
        }
      }
    }
    // online softmax: rows on (quad, r); reduce across the 16 l15 lanes
    float mnew[4];
#pragma unroll
    for (int r = 0; r < 4; r++)
      mnew[r] = fmaxf(fmaxf(s[0][r], s[1][r]), fmaxf(s[2][r], s[3][r]));
#pragma unroll
    for (int off = 1; off < 16; off <<= 1)
#pragma unroll
      for (int r = 0; r < 4; r++) mnew[r] = fmaxf(mnew[r], __shfl_xor(mnew[r], off));
    float alpha[4];
#pragma unroll
    for (int r = 0; r < 4; r++) {
      float mi = fmaxf(mr[r], mnew[r]);
      alpha[r] = __expf(mr[r] - mi);
      mr[r] = mi;
    }
    float p[4][4], rs[4];
#pragma unroll
    for (int n = 0; n < 4; n++)
#pragma unroll
      for (int r = 0; r < 4; r++) p[n][r] = __expf(s[n][r] - mr[r]);
#pragma unroll
    for (int r = 0; r < 4; r++) rs[r] = (p[0][r] + p[1][r]) + (p[2][r] + p[3][r]);
#pragma unroll
    for (int off = 1; off < 16; off <<= 1)
#pragma unroll
      for (int r = 0; r < 4; r++) rs[r] += __shfl_xor(rs[r], off);
#pragma unroll
    for (int r = 0; r < 4; r++) lr[r] = lr[r] * alpha[r] + rs[r];
#pragma unroll
    for (int n = 0; n < 8; n++)
#pragma unroll
      for (int r = 0; r < 4; r++) o[n][r] *= alpha[r];
    // P: C-layout -> A-layout via LDS (single wave: lgkmcnt ordering suffices)
    asm volatile("s_waitcnt lgkmcnt(0)" ::: "memory");  // prior pbuf reads done
#pragma unroll
    for (int n = 0; n < 4; n++)
#pragma unroll
      for (int r = 0; r < 4; r++)
        pbuf[(quad * 4 + r) * PP + n * 16 + l15] = f2bf(p[n][r]);
    asm volatile("s_waitcnt lgkmcnt(0)" ::: "memory");  // writes visible
    // O += P @ V (V pre-fetched above)
#pragma unroll
    for (int ks = 0; ks < 2; ks++) {
      bf16x8 pa = ldb8(pbuf + l15 * PP + ks * 32 + quad * 8);
#pragma unroll
      for (int n = 0; n < 8; n++)
        o[n] = __builtin_amdgcn_mfma_f32_16x16x32_bf16(pa, vf[ks][n], o[n], 0, 0, 0);
    }
  }
  float inv[4];
#pragma unroll
  for (int r = 0; r < 4; r++) inv[r] = 1.0f / lr[r];
  float* orow = out + ((size_t)b * T_ + q0 + quad * 4) * H_;
#pragma unroll
  for (int n = 0; n < 8; n++)
#pragma unroll
    for (int r = 0; r < 4; r++)
      orow[(size_t)r * H_ + n * 16 + l15] = o[n][r] * inv[r];
}

// ---------------------------------------------------------------------------
extern "C" void kernel_launch(void* const* d_in, const int* in_sizes, int n_in,
                              void* d_out, int out_size, void* d_ws, size_t ws_size,
                              hipStream_t stream) {
  const float* x  = (const float*)d_in[0];
  const float* Wq = (const float*)d_in[1];
  const float* Wk = (const float*)d_in[2];
  const float* Wv = (const float*)d_in[3];
  // ws layout (~22.3 MB), all u16:
  const size_t BTH = (size_t)B_ * T_ * H_;
  unsigned short* Whi = (unsigned short*)d_ws;   // 3*H*C
  unsigned short* Wlo = Whi + 3 * H_ * C_;       // 2*H*C (Q,K only)
  unsigned short* Vt  = Wlo + 2 * H_ * C_;       // BTH
  unsigned short* Qhi = Vt + BTH;
  unsigned short* Qlo = Qhi + BTH;
  unsigned short* Khi = Qlo + BTH;
  unsigned short* Klo = Khi + BTH;
  float* out = (float*)d_out;

  wt_k<<<dim3(32, 4, 3), dim3(32, 8), 0, stream>>>(Wq, Wk, Wv, Whi, Wlo);
  qkv_k<<<3 * (B_ * T_ / 64), 256, 0, stream>>>(x, Whi, Wlo, Qhi, Qlo, Khi, Klo, Vt);
  flash_k<<<B_ * (T_ / 16), 64, 0, stream>>>(Qhi, Qlo, Khi, Klo, Vt, out);
}